// Round 4
// baseline (2278.025 us; speedup 1.0000x reference)
//
#include <hip/hip_runtime.h>
#include <hip/hip_bf16.h>

#define HD 512      // d_model
#define NST 64      // d_state
#define NLAY 6
#define LSEQ 784
#define BB 64       // batch
#define QL 8        // lanes per channel
#define NS2 4       // float2-packed states per lane (8 complex states)

typedef float v2f __attribute__((ext_vector_type(2)));

#if __has_builtin(__builtin_elementwise_fma)
#define FMA2(a, b, c) __builtin_elementwise_fma((a), (b), (c))
#else
#define FMA2(a, b, c) ((a) * (b) + (c))
#endif

// DPP-based partial-wave reduction (no LDS, no lgkmcnt): after xor1+xor2
// (quad_perm) every lane holds its quad sum; row_half_mirror exchanges the
// two quads of each 8-lane group.
template <int CTRL>
__device__ __forceinline__ float dpp_add(float x)
{
    int xi = __builtin_bit_cast(int, x);
    int yi = __builtin_amdgcn_update_dpp(0, xi, CTRL, 0xF, 0xF, true);
    return x + __builtin_bit_cast(float, yi);
}

// ---------------------------------------------------------------------------
// Precompute lambda = exp(dt*A) and 2*Cd (ZOH-discretized C) per (layer,n,h),
// stored [layer][n][h] so scan lanes (consecutive h) load coalesced.
// ---------------------------------------------------------------------------
__global__ void precompute_k(const float* __restrict__ log_dt,
                             const float* __restrict__ log_A_real,
                             const float* __restrict__ A_imag,
                             const float* __restrict__ C_re,
                             const float* __restrict__ C_im,
                             float* __restrict__ lamr, float* __restrict__ lami,
                             float* __restrict__ cdr,  float* __restrict__ cdi)
{
    int t = blockIdx.x * blockDim.x + threadIdx.x;
    if (t >= NLAY * HD * NST) return;
    int n  = t % NST;
    int ih = t / NST;          // i*HD + h
    int i  = ih / HD;
    int h  = ih % HD;

    float dt  = expf(log_dt[ih]);
    float are = -expf(log_A_real[t]);
    float aim = A_imag[t];
    float dr = are * dt, di = aim * dt;
    float er = expf(dr);
    float sn, cs;
    __sincosf(di, &sn, &cs);
    float lr = er * cs, li = er * sn;  // lambda = exp(dt*A)
    // q = (lambda - 1) / A
    float e1r = lr - 1.0f, e1i = li;
    float den = are * are + aim * aim;
    float qr = (e1r * are + e1i * aim) / den;
    float qi = (e1i * are - e1r * aim) / den;
    float crv = C_re[t], civ = C_im[t];
    float cdre = crv * qr - civ * qi;
    float cdim = crv * qi + civ * qr;

    size_t o = ((size_t)i * NST + n) * HD + h;
    lamr[o] = lr; lami[o] = li;
    cdr[o] = 2.0f * cdre; cdi[o] = 2.0f * cdim;  // fold the 2*Re() factor
}

// ---------------------------------------------------------------------------
// Encoder: u[b,l,h] = x[b,l] * enc_w[h] + enc_b[h]
// ---------------------------------------------------------------------------
__global__ void encoder_k(const float* __restrict__ x, const float* __restrict__ ew,
                          const float* __restrict__ eb, float* __restrict__ u)
{
    size_t g = (size_t)blockIdx.x * blockDim.x + threadIdx.x;
    if (g >= (size_t)BB * LSEQ * HD) return;
    int h = (int)(g % HD);
    size_t bl = g / HD;
    u[g] = fmaf(x[bl], ew[h], eb[h]);
}

// ---------------------------------------------------------------------------
// Fused SSM scan + residual, IN PLACE on u.
// QL=8 lanes per (b,h) channel; lane octant o holds complex states
// o*8 .. o*8+7, packed SoA into 4 float2 so the recurrence is pure
// element-wise v_pk_* ops (VOP3P, 2x f32/issue).
// y partial sums combined across the 8 lanes with 3 DPP adds (no LDS).
// Then u_l <- u_l*(1+D[h]) + y_l (pre-LN residual value), lane o==0 stores.
// In-place safety: loads of an address (incl. depth-2 prefetch) precede the
// owning lane's store in wave program order; channels are address-disjoint
// across waves. 4096 waves -> 4 waves/SIMD.
// ---------------------------------------------------------------------------
__global__ __launch_bounds__(256, 4)
void scan_k(float* __restrict__ u,
            const float* __restrict__ lamr, const float* __restrict__ lami,
            const float* __restrict__ cdr,  const float* __restrict__ cdi,
            const float* __restrict__ Dvec)
{
    int g = blockIdx.x * 256 + threadIdx.x;   // 0 .. BB*HD*QL-1
    int ch  = g >> 3;                         // (b,h) flat
    int oct = g & 7;
    int h = ch & (HD - 1);
    int b = ch >> 9;                          // HD = 512
    int n0 = oct * (2 * NS2);
    float dcoef = 1.0f + Dvec[h];

    v2f lr[NS2], nli[NS2], li[NS2], cr[NS2], ci[NS2], sr[NS2], si[NS2];
#pragma unroll
    for (int j = 0; j < NS2; j++) {
        size_t o = (size_t)(n0 + 2 * j) * HD + h;   // states 2j, 2j+1 (stride HD)
        lr[j]  = v2f{lamr[o], lamr[o + HD]};
        li[j]  = v2f{lami[o], lami[o + HD]};
        nli[j] = -li[j];
        cr[j]  = v2f{cdr[o], cdr[o + HD]};
        ci[j]  = v2f{cdi[o], cdi[o + HD]};
        sr[j]  = v2f{0.f, 0.f};
        si[j]  = v2f{0.f, 0.f};
    }

    size_t idx = (size_t)b * LSEQ * HD + h;
    float u0 = u[idx];
    float u1 = u[idx + HD];
#pragma unroll 2
    for (int l = 0; l < LSEQ; l++) {
        float uv = u0;
        u0 = u1;
        u1 = u[idx + 2 * HD];   // depth-2 prefetch; U has 2*HD slack at end
        v2f uv2 = v2f{uv, uv};
        v2f ya = v2f{0.f, 0.f}, yb = v2f{0.f, 0.f};
#pragma unroll
        for (int j = 0; j < NS2; j++) {
            v2f t0  = FMA2(nli[j], si[j], uv2);
            v2f nsr = FMA2(lr[j], sr[j], t0);
            v2f tmp = li[j] * sr[j];
            v2f nsi = FMA2(lr[j], si[j], tmp);
            sr[j] = nsr; si[j] = nsi;
            ya = FMA2(cr[j], nsr, ya);
            yb = FMA2(ci[j], nsi, yb);
        }
        v2f yc = ya - yb;
        float y = yc.x + yc.y;
        y = dpp_add<0xB1>(y);    // quad_perm [1,0,3,2]  : xor 1
        y = dpp_add<0x4E>(y);    // quad_perm [2,3,0,1]  : xor 2
        y = dpp_add<0x141>(y);   // row_half_mirror      : cross-quad in 8
        if (oct == 0) u[idx] = fmaf(uv, dcoef, y);
        idx += HD;
    }
}

// ---------------------------------------------------------------------------
// In-place LayerNorm over H. One wave per (b,l) row; 8 floats per lane.
// ---------------------------------------------------------------------------
__global__ void ln_k(float* __restrict__ u, const float* __restrict__ gp,
                     const float* __restrict__ bp)
{
    int wid  = threadIdx.x >> 6;
    int lane = threadIdx.x & 63;
    size_t row = (size_t)blockIdx.x * 4 + wid;   // < BB*LSEQ exactly
    float* up = u + row * HD;

    float4 a0 = ((const float4*)up)[lane];
    float4 a1 = ((const float4*)up)[64 + lane];
    float v[8] = {a0.x, a0.y, a0.z, a0.w, a1.x, a1.y, a1.z, a1.w};
    int h0 = lane * 4, h1 = 256 + lane * 4;

    float s = 0.f;
#pragma unroll
    for (int j = 0; j < 8; j++) s += v[j];
#pragma unroll
    for (int m = 32; m >= 1; m >>= 1) s += __shfl_xor(s, m, 64);
    float mu = s * (1.0f / HD);

    float q = 0.f;
#pragma unroll
    for (int j = 0; j < 8; j++) { float d = v[j] - mu; q += d * d; }
#pragma unroll
    for (int m = 32; m >= 1; m >>= 1) q += __shfl_xor(q, m, 64);
    float rs = rsqrtf(q * (1.0f / HD) + 1e-5f);

    float o[8];
#pragma unroll
    for (int j = 0; j < 8; j++) {
        int h = (j < 4) ? (h0 + j) : (h1 + j - 4);
        o[j] = fmaf((v[j] - mu) * rs, gp[h], bp[h]);
    }
    ((float4*)up)[lane]      = {o[0], o[1], o[2], o[3]};
    ((float4*)up)[64 + lane] = {o[4], o[5], o[6], o[7]};
}

// ---------------------------------------------------------------------------
// Mean-pool over L: pooled[b,h] = mean_l u[b,l,h]
// ---------------------------------------------------------------------------
__global__ void pool_k(const float* __restrict__ u, float* __restrict__ p)
{
    int g = blockIdx.x * blockDim.x + threadIdx.x;
    if (g >= BB * HD) return;
    int h = g & (HD - 1);
    int b = g >> 9;
    const float* up = u + (size_t)b * LSEQ * HD + h;
    float s = 0.f;
    for (int l = 0; l < LSEQ; l++) s += up[(size_t)l * HD];
    p[g] = s * (1.0f / LSEQ);
}

// ---------------------------------------------------------------------------
// Decoder: out[b,c] = pooled[b,:] @ dec_w[:,c] + dec_b[c]
// ---------------------------------------------------------------------------
__global__ void dec_k(const float* __restrict__ p, const float* __restrict__ w,
                      const float* __restrict__ bias, float* __restrict__ out)
{
    int t = blockIdx.x * blockDim.x + threadIdx.x;
    if (t >= BB * 10) return;
    int c = t % 10, b = t / 10;
    float acc = bias[c];
    const float* pb = p + b * HD;
    for (int h = 0; h < HD; h++) acc = fmaf(pb[h], w[h * 10 + c], acc);
    out[t] = acc;
}

// ---------------------------------------------------------------------------
extern "C" void kernel_launch(void* const* d_in, const int* in_sizes, int n_in,
                              void* d_out, int out_size, void* d_ws, size_t ws_size,
                              hipStream_t stream)
{
    const float* x   = (const float*)d_in[0];
    const float* ew  = (const float*)d_in[1];
    const float* eb  = (const float*)d_in[2];
    const float* ldt = (const float*)d_in[3];
    const float* lar = (const float*)d_in[4];
    const float* aim = (const float*)d_in[5];
    const float* cre = (const float*)d_in[6];
    const float* cim = (const float*)d_in[7];
    const float* Dp  = (const float*)d_in[8];
    const float* lng = (const float*)d_in[9];
    const float* lnb = (const float*)d_in[10];
    const float* fng = (const float*)d_in[11];
    const float* fnb = (const float*)d_in[12];
    const float* dw  = (const float*)d_in[13];
    const float* db  = (const float*)d_in[14];
    float* out = (float*)d_out;

    float* ws = (float*)d_ws;
    const size_t SZ = (size_t)BB * LSEQ * HD;   // 25,690,112 floats (103 MB)
    const size_t P  = (size_t)NLAY * NST * HD;  // 196,608 floats
    float* U  = ws;                              // residual stream, in-place
    float* LR = ws + SZ + 2 * HD;                // 2*HD slack for prefetch
    float* LI = LR + P;
    float* CR = LI + P;
    float* CI = CR + P;
    float* PO = CI + P;                          // BB*HD floats
    // total: ~106 MB

    precompute_k<<<(NLAY * HD * NST + 255) / 256, 256, 0, stream>>>(
        ldt, lar, aim, cre, cim, LR, LI, CR, CI);
    encoder_k<<<(int)((SZ + 255) / 256), 256, 0, stream>>>(x, ew, eb, U);

    for (int i = 0; i < NLAY; i++) {
        size_t po = (size_t)i * NST * HD;
        scan_k<<<BB * HD * QL / 256, 256, 0, stream>>>(
            U, LR + po, LI + po, CR + po, CI + po, Dp + i * HD);
        ln_k<<<BB * LSEQ / 4, 256, 0, stream>>>(U, lng + i * HD, lnb + i * HD);
    }
    ln_k<<<BB * LSEQ / 4, 256, 0, stream>>>(U, fng, fnb);
    pool_k<<<BB * HD / 256, 256, 0, stream>>>(U, PO);
    dec_k<<<(BB * 10 + 255) / 256, 256, 0, stream>>>(PO, dw, db, out);
}

// Round 5
// 2036.888 us; speedup vs baseline: 1.1184x; 1.1184x over previous
//
#include <hip/hip_runtime.h>
#include <hip/hip_bf16.h>

#define HD 512      // d_model
#define NST 64      // d_state
#define NLAY 6
#define LSEQ 784
#define BB 64       // batch
#define QL 8        // lanes per channel
#define NS2 4       // float2-packed states per lane (8 complex states)

typedef float v2f __attribute__((ext_vector_type(2)));

// Packed f32 math, forced via inline asm (VOP3P, 2x f32 per issue slot).
// "v" constraints pin operands to VGPRs -> also blocks AGPR demotion.
__device__ __forceinline__ v2f pk_fma(v2f a, v2f b, v2f c)
{
    v2f d;
    asm("v_pk_fma_f32 %0, %1, %2, %3" : "=v"(d) : "v"(a), "v"(b), "v"(c));
    return d;
}
__device__ __forceinline__ v2f pk_mul(v2f a, v2f b)
{
    v2f d;
    asm("v_pk_mul_f32 %0, %1, %2" : "=v"(d) : "v"(a), "v"(b));
    return d;
}

// DPP-based 8-lane reduction (no LDS): xor1 + xor2 (quad_perm) then
// row_half_mirror; afterwards ALL 8 lanes of the group hold the total.
template <int CTRL>
__device__ __forceinline__ float dpp_add(float x)
{
    int xi = __builtin_bit_cast(int, x);
    int yi = __builtin_amdgcn_update_dpp(0, xi, CTRL, 0xF, 0xF, true);
    return x + __builtin_bit_cast(float, yi);
}

// ---------------------------------------------------------------------------
// Precompute lambda = exp(dt*A) and 2*Cd (ZOH-discretized C) per (layer,n,h),
// stored [layer][n][h] so scan lanes (consecutive h) load coalesced.
// ---------------------------------------------------------------------------
__global__ void precompute_k(const float* __restrict__ log_dt,
                             const float* __restrict__ log_A_real,
                             const float* __restrict__ A_imag,
                             const float* __restrict__ C_re,
                             const float* __restrict__ C_im,
                             float* __restrict__ lamr, float* __restrict__ lami,
                             float* __restrict__ cdr,  float* __restrict__ cdi)
{
    int t = blockIdx.x * blockDim.x + threadIdx.x;
    if (t >= NLAY * HD * NST) return;
    int n  = t % NST;
    int ih = t / NST;          // i*HD + h
    int i  = ih / HD;
    int h  = ih % HD;

    float dt  = expf(log_dt[ih]);
    float are = -expf(log_A_real[t]);
    float aim = A_imag[t];
    float dr = are * dt, di = aim * dt;
    float er = expf(dr);
    float sn, cs;
    __sincosf(di, &sn, &cs);
    float lr = er * cs, li = er * sn;  // lambda = exp(dt*A)
    // q = (lambda - 1) / A
    float e1r = lr - 1.0f, e1i = li;
    float den = are * are + aim * aim;
    float qr = (e1r * are + e1i * aim) / den;
    float qi = (e1i * are - e1r * aim) / den;
    float crv = C_re[t], civ = C_im[t];
    float cdre = crv * qr - civ * qi;
    float cdim = crv * qi + civ * qr;

    size_t o = ((size_t)i * NST + n) * HD + h;
    lamr[o] = lr; lami[o] = li;
    cdr[o] = 2.0f * cdre; cdi[o] = 2.0f * cdim;  // fold the 2*Re() factor
}

// ---------------------------------------------------------------------------
// Encoder: u[b,l,h] = x[b,l] * enc_w[h] + enc_b[h]
// ---------------------------------------------------------------------------
__global__ void encoder_k(const float* __restrict__ x, const float* __restrict__ ew,
                          const float* __restrict__ eb, float* __restrict__ u)
{
    size_t g = (size_t)blockIdx.x * blockDim.x + threadIdx.x;
    if (g >= (size_t)BB * LSEQ * HD) return;
    int h = (int)(g % HD);
    size_t bl = g / HD;
    u[g] = fmaf(x[bl], ew[h], eb[h]);
}

// ---------------------------------------------------------------------------
// Fused SSM scan + residual, IN PLACE on u.
// QL=8 lanes per (b,h) channel; lane octant o holds complex states
// o*8..o*8+7 packed SoA into float2 -> recurrence is pure v_pk_* asm.
// y partials combined across 8 lanes with 3 DPP adds; lane 0 stores
// u_l <- u_l*(1+D[h]) + y_l (pre-LN residual value).
// Depth-4 prefetch (unroll 4) covers ~900cyc HBM latency at 4 waves/SIMD.
// In-place safety: loads of an address (incl. prefetch) precede the owning
// lane's store in wave program order; channels are address-disjoint.
// launch_bounds(256,2): 256-VGPR budget -> no AGPR demotion of state.
// ---------------------------------------------------------------------------
__global__ __launch_bounds__(256, 2)
void scan_k(float* __restrict__ u,
            const float* __restrict__ lamr, const float* __restrict__ lami,
            const float* __restrict__ cdr,  const float* __restrict__ cdi,
            const float* __restrict__ Dvec)
{
    int g = blockIdx.x * 256 + threadIdx.x;   // 0 .. BB*HD*QL-1
    int ch  = g >> 3;                         // (b,h) flat
    int oct = g & 7;
    int h = ch & (HD - 1);
    int b = ch >> 9;                          // HD = 512
    int n0 = oct * (2 * NS2);
    float dcoef = 1.0f + Dvec[h];

    v2f lr[NS2], nli[NS2], li[NS2], cr[NS2], ci[NS2], sr[NS2], si[NS2];
#pragma unroll
    for (int j = 0; j < NS2; j++) {
        size_t o = (size_t)(n0 + 2 * j) * HD + h;   // states 2j, 2j+1
        lr[j]  = v2f{lamr[o], lamr[o + HD]};
        li[j]  = v2f{lami[o], lami[o + HD]};
        nli[j] = -li[j];
        cr[j]  = v2f{cdr[o], cdr[o + HD]};
        ci[j]  = v2f{cdi[o], cdi[o + HD]};
        sr[j]  = v2f{0.f, 0.f};
        si[j]  = v2f{0.f, 0.f};
    }

    size_t idx = (size_t)b * LSEQ * HD + h;
    float ub0 = u[idx];
    float ub1 = u[idx + HD];
    float ub2 = u[idx + 2 * HD];
    float ub3 = u[idx + 3 * HD];
#pragma unroll 4
    for (int l = 0; l < LSEQ; l++) {
        float uv = ub0;
        ub0 = ub1; ub1 = ub2; ub2 = ub3;
        ub3 = u[idx + 4 * HD];   // depth-4 prefetch; U has 4*HD slack
        v2f uv2 = v2f{uv, uv};
        v2f ya = v2f{0.f, 0.f}, yb = v2f{0.f, 0.f};
#pragma unroll
        for (int j = 0; j < NS2; j++) {
            v2f t0  = pk_fma(nli[j], si[j], uv2);
            v2f nsr = pk_fma(lr[j], sr[j], t0);
            v2f tmp = pk_mul(li[j], sr[j]);
            v2f nsi = pk_fma(lr[j], si[j], tmp);
            sr[j] = nsr; si[j] = nsi;
            ya = pk_fma(cr[j], nsr, ya);
            yb = pk_fma(ci[j], nsi, yb);
        }
        v2f yc = ya - yb;
        float y = yc.x + yc.y;
        y = dpp_add<0xB1>(y);    // quad_perm xor 1
        y = dpp_add<0x4E>(y);    // quad_perm xor 2
        y = dpp_add<0x141>(y);   // row_half_mirror: cross-quad within 8
        if (oct == 0) u[idx] = fmaf(uv, dcoef, y);
        idx += HD;
    }
}

// ---------------------------------------------------------------------------
// In-place LayerNorm over H. One wave per (b,l) row; 8 floats per lane.
// ---------------------------------------------------------------------------
__global__ void ln_k(float* __restrict__ u, const float* __restrict__ gp,
                     const float* __restrict__ bp)
{
    int wid  = threadIdx.x >> 6;
    int lane = threadIdx.x & 63;
    size_t row = (size_t)blockIdx.x * 4 + wid;   // < BB*LSEQ exactly
    float* up = u + row * HD;

    float4 a0 = ((const float4*)up)[lane];
    float4 a1 = ((const float4*)up)[64 + lane];
    float v[8] = {a0.x, a0.y, a0.z, a0.w, a1.x, a1.y, a1.z, a1.w};
    int h0 = lane * 4, h1 = 256 + lane * 4;

    float s = 0.f;
#pragma unroll
    for (int j = 0; j < 8; j++) s += v[j];
#pragma unroll
    for (int m = 32; m >= 1; m >>= 1) s += __shfl_xor(s, m, 64);
    float mu = s * (1.0f / HD);

    float q = 0.f;
#pragma unroll
    for (int j = 0; j < 8; j++) { float d = v[j] - mu; q += d * d; }
#pragma unroll
    for (int m = 32; m >= 1; m >>= 1) q += __shfl_xor(q, m, 64);
    float rs = rsqrtf(q * (1.0f / HD) + 1e-5f);

    float o[8];
#pragma unroll
    for (int j = 0; j < 8; j++) {
        int h = (j < 4) ? (h0 + j) : (h1 + j - 4);
        o[j] = fmaf((v[j] - mu) * rs, gp[h], bp[h]);
    }
    ((float4*)up)[lane]      = {o[0], o[1], o[2], o[3]};
    ((float4*)up)[64 + lane] = {o[4], o[5], o[6], o[7]};
}

// ---------------------------------------------------------------------------
// Mean-pool over L: pooled[b,h] = mean_l u[b,l,h]
// ---------------------------------------------------------------------------
__global__ void pool_k(const float* __restrict__ u, float* __restrict__ p)
{
    int g = blockIdx.x * blockDim.x + threadIdx.x;
    if (g >= BB * HD) return;
    int h = g & (HD - 1);
    int b = g >> 9;
    const float* up = u + (size_t)b * LSEQ * HD + h;
    float s = 0.f;
    for (int l = 0; l < LSEQ; l++) s += up[(size_t)l * HD];
    p[g] = s * (1.0f / LSEQ);
}

// ---------------------------------------------------------------------------
// Decoder: out[b,c] = pooled[b,:] @ dec_w[:,c] + dec_b[c]
// ---------------------------------------------------------------------------
__global__ void dec_k(const float* __restrict__ p, const float* __restrict__ w,
                      const float* __restrict__ bias, float* __restrict__ out)
{
    int t = blockIdx.x * blockDim.x + threadIdx.x;
    if (t >= BB * 10) return;
    int c = t % 10, b = t / 10;
    float acc = bias[c];
    const float* pb = p + b * HD;
    for (int h = 0; h < HD; h++) acc = fmaf(pb[h], w[h * 10 + c], acc);
    out[t] = acc;
}

// ---------------------------------------------------------------------------
extern "C" void kernel_launch(void* const* d_in, const int* in_sizes, int n_in,
                              void* d_out, int out_size, void* d_ws, size_t ws_size,
                              hipStream_t stream)
{
    const float* x   = (const float*)d_in[0];
    const float* ew  = (const float*)d_in[1];
    const float* eb  = (const float*)d_in[2];
    const float* ldt = (const float*)d_in[3];
    const float* lar = (const float*)d_in[4];
    const float* aim = (const float*)d_in[5];
    const float* cre = (const float*)d_in[6];
    const float* cim = (const float*)d_in[7];
    const float* Dp  = (const float*)d_in[8];
    const float* lng = (const float*)d_in[9];
    const float* lnb = (const float*)d_in[10];
    const float* fng = (const float*)d_in[11];
    const float* fnb = (const float*)d_in[12];
    const float* dw  = (const float*)d_in[13];
    const float* db  = (const float*)d_in[14];
    float* out = (float*)d_out;

    float* ws = (float*)d_ws;
    const size_t SZ = (size_t)BB * LSEQ * HD;   // 25,690,112 floats (103 MB)
    const size_t P  = (size_t)NLAY * NST * HD;  // 196,608 floats
    float* U  = ws;                              // residual stream, in-place
    float* LR = ws + SZ + 4 * HD;                // 4*HD slack for prefetch
    float* LI = LR + P;
    float* CR = LI + P;
    float* CI = CR + P;
    float* PO = CI + P;                          // BB*HD floats
    // total: ~106 MB

    precompute_k<<<(NLAY * HD * NST + 255) / 256, 256, 0, stream>>>(
        ldt, lar, aim, cre, cim, LR, LI, CR, CI);
    encoder_k<<<(int)((SZ + 255) / 256), 256, 0, stream>>>(x, ew, eb, U);

    for (int i = 0; i < NLAY; i++) {
        size_t po = (size_t)i * NST * HD;
        scan_k<<<BB * HD * QL / 256, 256, 0, stream>>>(
            U, LR + po, LI + po, CR + po, CI + po, Dp + i * HD);
        ln_k<<<BB * LSEQ / 4, 256, 0, stream>>>(U, lng + i * HD, lnb + i * HD);
    }
    ln_k<<<BB * LSEQ / 4, 256, 0, stream>>>(U, fng, fnb);
    pool_k<<<BB * HD / 256, 256, 0, stream>>>(U, PO);
    dec_k<<<(BB * 10 + 255) / 256, 256, 0, stream>>>(PO, dw, db, out);
}

// Round 6
// 1940.607 us; speedup vs baseline: 1.1739x; 1.0496x over previous
//
#include <hip/hip_runtime.h>
#include <hip/hip_bf16.h>

#define HD 512      // d_model
#define NST 64      // d_state
#define NLAY 6
#define LSEQ 784
#define BB 64       // batch
#define QL 4        // lanes per channel
#define NS2 8       // float2-packed states per lane (16 complex states)
#define TL 64       // l-steps per LDS tile
#define CHB 64      // channels per block (256 thr / QL)

typedef float v2f __attribute__((ext_vector_type(2)));

// Packed f32 math via inline asm (VOP3P, 2x f32 per issue slot). "v"
// constraints pin operands to VGPRs (blocks AGPR demotion of hot values).
__device__ __forceinline__ v2f pk_fma(v2f a, v2f b, v2f c)
{
    v2f d;
    asm("v_pk_fma_f32 %0, %1, %2, %3" : "=v"(d) : "v"(a), "v"(b), "v"(c));
    return d;
}
// d = (-a)*b + c   (neg modifier on src0, both halves)
__device__ __forceinline__ v2f pk_fma_na(v2f a, v2f b, v2f c)
{
    v2f d;
    asm("v_pk_fma_f32 %0, %1, %2, %3 neg_lo:[1,0,0] neg_hi:[1,0,0]"
        : "=v"(d) : "v"(a), "v"(b), "v"(c));
    return d;
}
__device__ __forceinline__ v2f pk_mul(v2f a, v2f b)
{
    v2f d;
    asm("v_pk_mul_f32 %0, %1, %2" : "=v"(d) : "v"(a), "v"(b));
    return d;
}

// DPP add over 4-lane groups: xor1 + xor2 (quad_perm); all 4 lanes end with
// the quad total. Pure VALU, no LDS/lgkmcnt.
template <int CTRL>
__device__ __forceinline__ float dpp_add(float x)
{
    int xi = __builtin_bit_cast(int, x);
    int yi = __builtin_amdgcn_update_dpp(0, xi, CTRL, 0xF, 0xF, true);
    return x + __builtin_bit_cast(float, yi);
}

// ---------------------------------------------------------------------------
// Precompute lambda = exp(dt*A) and 2*Cd (ZOH-discretized C) per (layer,n,h),
// stored [layer][n][h] so scan lanes (consecutive h) load coalesced.
// ---------------------------------------------------------------------------
__global__ void precompute_k(const float* __restrict__ log_dt,
                             const float* __restrict__ log_A_real,
                             const float* __restrict__ A_imag,
                             const float* __restrict__ C_re,
                             const float* __restrict__ C_im,
                             float* __restrict__ lamr, float* __restrict__ lami,
                             float* __restrict__ cdr,  float* __restrict__ cdi)
{
    int t = blockIdx.x * blockDim.x + threadIdx.x;
    if (t >= NLAY * HD * NST) return;
    int n  = t % NST;
    int ih = t / NST;          // i*HD + h
    int i  = ih / HD;
    int h  = ih % HD;

    float dt  = expf(log_dt[ih]);
    float are = -expf(log_A_real[t]);
    float aim = A_imag[t];
    float dr = are * dt, di = aim * dt;
    float er = expf(dr);
    float sn, cs;
    __sincosf(di, &sn, &cs);
    float lr = er * cs, li = er * sn;  // lambda = exp(dt*A)
    // q = (lambda - 1) / A
    float e1r = lr - 1.0f, e1i = li;
    float den = are * are + aim * aim;
    float qr = (e1r * are + e1i * aim) / den;
    float qi = (e1i * are - e1r * aim) / den;
    float crv = C_re[t], civ = C_im[t];
    float cdre = crv * qr - civ * qi;
    float cdim = crv * qi + civ * qr;

    size_t o = ((size_t)i * NST + n) * HD + h;
    lamr[o] = lr; lami[o] = li;
    cdr[o] = 2.0f * cdre; cdi[o] = 2.0f * cdim;  // fold the 2*Re() factor
}

// ---------------------------------------------------------------------------
// Encoder: u[b,l,h] = x[b,l] * enc_w[h] + enc_b[h]
// ---------------------------------------------------------------------------
__global__ void encoder_k(const float* __restrict__ x, const float* __restrict__ ew,
                          const float* __restrict__ eb, float* __restrict__ u)
{
    size_t g = (size_t)blockIdx.x * blockDim.x + threadIdx.x;
    if (g >= (size_t)BB * LSEQ * HD) return;
    int h = (int)(g % HD);
    size_t bl = g / HD;
    u[g] = fmaf(x[bl], ew[h], eb[h]);
}

// ---------------------------------------------------------------------------
// Fused SSM scan + residual, IN PLACE on u, LDS-staged.
// Block = 64 channels (one b, 64 consecutive h) x QL=4 lanes each.
// Lane quarter q holds complex states q*16..q*16+15, packed SoA in float2
// (v_pk_* ops). U is staged tile-by-tile (TL=64 l-steps) into LDS with
// fully-coalesced float4 loads, register-double-buffered so the global
// loads for tile t+1 are issued before computing tile t (latency hidden).
// Compute reads LDS only (16 consecutive banks x 4-lane broadcast,
// conflict-free); the per-step masked global store is fire-and-forget —
// no vmcnt wait in the compute path.
// y partials combined across the 4 lanes with 2 quad_perm DPP adds.
// In-place safety: stores target tile t's region, staged loads read tile
// t+1's region (disjoint), and each channel is owned by exactly one block.
// ---------------------------------------------------------------------------
__global__ __launch_bounds__(256, 2)
void scan_k(float* __restrict__ u,
            const float* __restrict__ lamr, const float* __restrict__ lami,
            const float* __restrict__ cdr,  const float* __restrict__ cdi,
            const float* __restrict__ Dvec)
{
    __shared__ float tile[TL * CHB];

    int thr = threadIdx.x;
    int ch0 = blockIdx.x * CHB;           // flat channel base (b*HD + h)
    int b   = ch0 >> 9;                   // HD = 512
    int h0  = ch0 & (HD - 1);
    int cl  = thr >> 2;                   // channel within block (0..63)
    int q   = thr & 3;                    // state quarter
    int h   = h0 + cl;
    int n0  = q * (2 * NS2);
    float dcoef = 1.0f + Dvec[h];

    v2f lr[NS2], li[NS2], cr[NS2], ci[NS2], sr[NS2], si[NS2];
#pragma unroll
    for (int j = 0; j < NS2; j++) {
        size_t o = (size_t)(n0 + 2 * j) * HD + h;   // states 2j, 2j+1
        lr[j] = v2f{lamr[o], lamr[o + HD]};
        li[j] = v2f{lami[o], lami[o + HD]};
        cr[j] = v2f{cdr[o], cdr[o + HD]};
        ci[j] = v2f{cdi[o], cdi[o + HD]};
        sr[j] = v2f{0.f, 0.f};
        si[j] = v2f{0.f, 0.f};
    }

    // staging thread mapping: 16 float4-cols x 16 rows per pass, 4 passes
    int scol = (thr & 15) * 4;            // float offset within row
    int srow = thr >> 4;                  // row within pass-group
    const int NT = (LSEQ + TL - 1) / TL;  // 13 (12 full + 16-tail)

    float4 pre[4];
    {   // prefetch tile 0
        int tl0 = TL;                      // tile 0 is full
        (void)tl0;
#pragma unroll
        for (int p = 0; p < 4; p++) {
            int row = p * 16 + srow;
            pre[p] = *(const float4*)&u[((size_t)b * LSEQ + row) * HD + h0 + scol];
        }
    }

    size_t gidx = (size_t)b * LSEQ * HD + h;   // store cursor for lane's ch

    for (int t = 0; t < NT; t++) {
        int l0 = t * TL;
        int tl = (LSEQ - l0 < TL) ? (LSEQ - l0) : TL;

        __syncthreads();                   // previous tile's LDS reads done
#pragma unroll
        for (int p = 0; p < 4; p++) {
            int row = p * 16 + srow;
            if (row < tl)
                *(float4*)&tile[row * CHB + scol] = pre[p];
        }
        __syncthreads();

        if (t + 1 < NT) {                  // issue next tile's loads NOW
            int l0n = l0 + TL;
            int tln = (LSEQ - l0n < TL) ? (LSEQ - l0n) : TL;
#pragma unroll
            for (int p = 0; p < 4; p++) {
                int row = p * 16 + srow;
                if (row < tln)
                    pre[p] = *(const float4*)&u[((size_t)b * LSEQ + l0n + row) * HD + h0 + scol];
            }
        }

        float uvn = tile[cl];              // prefetch l=0 of this tile
        for (int l = 0; l < tl; l++) {
            float uv = uvn;
            int ln = (l + 1 < tl) ? (l + 1) : l;
            uvn = tile[ln * CHB + cl];
            v2f uv2 = v2f{uv, uv};
            v2f ya = v2f{0.f, 0.f}, yb = v2f{0.f, 0.f};
#pragma unroll
            for (int j = 0; j < NS2; j++) {
                v2f t0  = pk_fma_na(li[j], si[j], uv2);   // -li*si + uv
                v2f nsr = pk_fma(lr[j], sr[j], t0);
                v2f tmp = pk_mul(li[j], sr[j]);
                v2f nsi = pk_fma(lr[j], si[j], tmp);
                sr[j] = nsr; si[j] = nsi;
                ya = pk_fma(cr[j], nsr, ya);
                yb = pk_fma(ci[j], nsi, yb);
            }
            v2f yc = ya - yb;
            float y = yc.x + yc.y;
            y = dpp_add<0xB1>(y);          // quad_perm xor 1
            y = dpp_add<0x4E>(y);          // quad_perm xor 2
            if (q == 0) u[gidx] = fmaf(uv, dcoef, y);
            gidx += HD;
        }
    }
}

// ---------------------------------------------------------------------------
// In-place LayerNorm over H. One wave per (b,l) row; 8 floats per lane.
// ---------------------------------------------------------------------------
__global__ void ln_k(float* __restrict__ u, const float* __restrict__ gp,
                     const float* __restrict__ bp)
{
    int wid  = threadIdx.x >> 6;
    int lane = threadIdx.x & 63;
    size_t row = (size_t)blockIdx.x * 4 + wid;   // < BB*LSEQ exactly
    float* up = u + row * HD;

    float4 a0 = ((const float4*)up)[lane];
    float4 a1 = ((const float4*)up)[64 + lane];
    float v[8] = {a0.x, a0.y, a0.z, a0.w, a1.x, a1.y, a1.z, a1.w};
    int h0 = lane * 4, h1 = 256 + lane * 4;

    float s = 0.f;
#pragma unroll
    for (int j = 0; j < 8; j++) s += v[j];
#pragma unroll
    for (int m = 32; m >= 1; m >>= 1) s += __shfl_xor(s, m, 64);
    float mu = s * (1.0f / HD);

    float qq = 0.f;
#pragma unroll
    for (int j = 0; j < 8; j++) { float d = v[j] - mu; qq += d * d; }
#pragma unroll
    for (int m = 32; m >= 1; m >>= 1) qq += __shfl_xor(qq, m, 64);
    float rs = rsqrtf(qq * (1.0f / HD) + 1e-5f);

    float o[8];
#pragma unroll
    for (int j = 0; j < 8; j++) {
        int h = (j < 4) ? (h0 + j) : (h1 + j - 4);
        o[j] = fmaf((v[j] - mu) * rs, gp[h], bp[h]);
    }
    ((float4*)up)[lane]      = {o[0], o[1], o[2], o[3]};
    ((float4*)up)[64 + lane] = {o[4], o[5], o[6], o[7]};
}

// ---------------------------------------------------------------------------
// Mean-pool over L: pooled[b,h] = mean_l u[b,l,h]
// ---------------------------------------------------------------------------
__global__ void pool_k(const float* __restrict__ u, float* __restrict__ p)
{
    int g = blockIdx.x * blockDim.x + threadIdx.x;
    if (g >= BB * HD) return;
    int h = g & (HD - 1);
    int b = g >> 9;
    const float* up = u + (size_t)b * LSEQ * HD + h;
    float s = 0.f;
    for (int l = 0; l < LSEQ; l++) s += up[(size_t)l * HD];
    p[g] = s * (1.0f / LSEQ);
}

// ---------------------------------------------------------------------------
// Decoder: out[b,c] = pooled[b,:] @ dec_w[:,c] + dec_b[c]
// ---------------------------------------------------------------------------
__global__ void dec_k(const float* __restrict__ p, const float* __restrict__ w,
                      const float* __restrict__ bias, float* __restrict__ out)
{
    int t = blockIdx.x * blockDim.x + threadIdx.x;
    if (t >= BB * 10) return;
    int c = t % 10, b = t / 10;
    float acc = bias[c];
    const float* pb = p + b * HD;
    for (int h = 0; h < HD; h++) acc = fmaf(pb[h], w[h * 10 + c], acc);
    out[t] = acc;
}

// ---------------------------------------------------------------------------
extern "C" void kernel_launch(void* const* d_in, const int* in_sizes, int n_in,
                              void* d_out, int out_size, void* d_ws, size_t ws_size,
                              hipStream_t stream)
{
    const float* x   = (const float*)d_in[0];
    const float* ew  = (const float*)d_in[1];
    const float* eb  = (const float*)d_in[2];
    const float* ldt = (const float*)d_in[3];
    const float* lar = (const float*)d_in[4];
    const float* aim = (const float*)d_in[5];
    const float* cre = (const float*)d_in[6];
    const float* cim = (const float*)d_in[7];
    const float* Dp  = (const float*)d_in[8];
    const float* lng = (const float*)d_in[9];
    const float* lnb = (const float*)d_in[10];
    const float* fng = (const float*)d_in[11];
    const float* fnb = (const float*)d_in[12];
    const float* dw  = (const float*)d_in[13];
    const float* db  = (const float*)d_in[14];
    float* out = (float*)d_out;

    float* ws = (float*)d_ws;
    const size_t SZ = (size_t)BB * LSEQ * HD;   // 25,690,112 floats (103 MB)
    const size_t P  = (size_t)NLAY * NST * HD;  // 196,608 floats
    float* U  = ws;                              // residual stream, in-place
    float* LR = ws + SZ + 4 * HD;
    float* LI = LR + P;
    float* CR = LI + P;
    float* CI = CR + P;
    float* PO = CI + P;                          // BB*HD floats
    // total: ~106 MB

    precompute_k<<<(NLAY * HD * NST + 255) / 256, 256, 0, stream>>>(
        ldt, lar, aim, cre, cim, LR, LI, CR, CI);
    encoder_k<<<(int)((SZ + 255) / 256), 256, 0, stream>>>(x, ew, eb, U);

    for (int i = 0; i < NLAY; i++) {
        size_t po = (size_t)i * NST * HD;
        scan_k<<<BB * HD / CHB, 256, 0, stream>>>(
            U, LR + po, LI + po, CR + po, CI + po, Dp + i * HD);
        ln_k<<<BB * LSEQ / 4, 256, 0, stream>>>(U, lng + i * HD, lnb + i * HD);
    }
    ln_k<<<BB * LSEQ / 4, 256, 0, stream>>>(U, fng, fnb);
    pool_k<<<BB * HD / 256, 256, 0, stream>>>(U, PO);
    dec_k<<<(BB * 10 + 255) / 256, 256, 0, stream>>>(PO, dw, db, out);
}

// Round 7
// 1855.496 us; speedup vs baseline: 1.2277x; 1.0459x over previous
//
#include <hip/hip_runtime.h>
#include <hip/hip_bf16.h>

#define HD 512      // d_model
#define NST 64      // d_state
#define NLAY 6
#define LSEQ 784
#define BB 64       // batch
#define QL 8        // lanes per channel
#define NS2 4       // float2-packed states per lane (8 complex states)
#define TL 112      // l-steps per LDS tile: 784 = 7*112, zero tail
#define CHB 64      // channels per block
#define NT 7        // tiles per sequence

typedef float v2f __attribute__((ext_vector_type(2)));

// Packed f32 math via inline asm (VOP3P). NOTE: same FLOP rate as scalar
// (datapath-limited); used for code density + blocking AGPR demotion.
__device__ __forceinline__ v2f pk_fma(v2f a, v2f b, v2f c)
{
    v2f d;
    asm("v_pk_fma_f32 %0, %1, %2, %3" : "=v"(d) : "v"(a), "v"(b), "v"(c));
    return d;
}
// d = (-a)*b + c
__device__ __forceinline__ v2f pk_fma_na(v2f a, v2f b, v2f c)
{
    v2f d;
    asm("v_pk_fma_f32 %0, %1, %2, %3 neg_lo:[1,0,0] neg_hi:[1,0,0]"
        : "=v"(d) : "v"(a), "v"(b), "v"(c));
    return d;
}
__device__ __forceinline__ v2f pk_mul(v2f a, v2f b)
{
    v2f d;
    asm("v_pk_mul_f32 %0, %1, %2" : "=v"(d) : "v"(a), "v"(b));
    return d;
}

// DPP adds: xor1 + xor2 (quad_perm) + row_half_mirror -> all 8 lanes of a
// group hold the 8-lane total. Pure VALU.
template <int CTRL>
__device__ __forceinline__ float dpp_add(float x)
{
    int xi = __builtin_bit_cast(int, x);
    int yi = __builtin_amdgcn_update_dpp(0, xi, CTRL, 0xF, 0xF, true);
    return x + __builtin_bit_cast(float, yi);
}

// ---------------------------------------------------------------------------
// Precompute lambda = exp(dt*A) and 2*Cd per (layer,n,h), [layer][n][h].
// ---------------------------------------------------------------------------
__global__ void precompute_k(const float* __restrict__ log_dt,
                             const float* __restrict__ log_A_real,
                             const float* __restrict__ A_imag,
                             const float* __restrict__ C_re,
                             const float* __restrict__ C_im,
                             float* __restrict__ lamr, float* __restrict__ lami,
                             float* __restrict__ cdr,  float* __restrict__ cdi)
{
    int t = blockIdx.x * blockDim.x + threadIdx.x;
    if (t >= NLAY * HD * NST) return;
    int n  = t % NST;
    int ih = t / NST;          // i*HD + h
    int i  = ih / HD;
    int h  = ih % HD;

    float dt  = expf(log_dt[ih]);
    float are = -expf(log_A_real[t]);
    float aim = A_imag[t];
    float dr = are * dt, di = aim * dt;
    float er = expf(dr);
    float sn, cs;
    __sincosf(di, &sn, &cs);
    float lr = er * cs, li = er * sn;  // lambda = exp(dt*A)
    float e1r = lr - 1.0f, e1i = li;
    float den = are * are + aim * aim;
    float qr = (e1r * are + e1i * aim) / den;
    float qi = (e1i * are - e1r * aim) / den;
    float crv = C_re[t], civ = C_im[t];
    float cdre = crv * qr - civ * qi;
    float cdim = crv * qi + civ * qr;

    size_t o = ((size_t)i * NST + n) * HD + h;
    lamr[o] = lr; lami[o] = li;
    cdr[o] = 2.0f * cdre; cdi[o] = 2.0f * cdim;
}

// ---------------------------------------------------------------------------
// Encoder: u[b,l,h] = x[b,l] * enc_w[h] + enc_b[h]
// ---------------------------------------------------------------------------
__global__ void encoder_k(const float* __restrict__ x, const float* __restrict__ ew,
                          const float* __restrict__ eb, float* __restrict__ u)
{
    size_t g = (size_t)blockIdx.x * blockDim.x + threadIdx.x;
    if (g >= (size_t)BB * LSEQ * HD) return;
    int h = (int)(g % HD);
    size_t bl = g / HD;
    u[g] = fmaf(x[bl], ew[h], eb[h]);
}

// ---------------------------------------------------------------------------
// Fused SSM scan + residual, IN PLACE on u, LDS-staged, zero-tail tiling.
// Block = 512 thr = 64 channels (one b, 64 consecutive h) x QL=8 lanes.
// Lane group-of-8 member q holds complex states q*8..q*8+7 (NS2=4 float2).
// Per tile (TL=112 l-steps): stage U tile to LDS via coalesced float4;
// issue next tile's global loads immediately (consumed ~13k cyc later ->
// HBM latency structurally hidden); compute loop reads LDS (8 banks x
// 8-lane broadcast, conflict-free), y combined with 3 DPP adds, result
// written back into the tile slot (input already consumed), then the tile
// is bulk-stored with coalesced float4 (no per-step global stores).
// 4096 waves = 4 waves/SIMD; inner loop has compile-time trip count
// (784 = 7*112) -> immediate LDS offsets + cross-iteration ILP.
// ---------------------------------------------------------------------------
__global__ __launch_bounds__(512, 4)
void scan_k(float* __restrict__ u,
            const float* __restrict__ lamr, const float* __restrict__ lami,
            const float* __restrict__ cdr,  const float* __restrict__ cdi,
            const float* __restrict__ Dvec)
{
    __shared__ float tile[TL * CHB];   // 28 KB

    const int thr = threadIdx.x;
    const int ch0 = blockIdx.x * CHB;     // flat channel base (b*HD + h0)
    const int b   = ch0 >> 9;             // HD = 512
    const int h0  = ch0 & (HD - 1);
    const int cl  = thr >> 3;             // channel within block (0..63)
    const int q   = thr & 7;              // state octant
    const int h   = h0 + cl;
    const int n0  = q * (2 * NS2);        // first state index (step 8)
    const float dcoef = 1.0f + Dvec[h];

    v2f lr[NS2], lim[NS2], cr[NS2], nci[NS2], sr[NS2], si[NS2];
#pragma unroll
    for (int j = 0; j < NS2; j++) {
        size_t o = (size_t)(n0 + 2 * j) * HD + h;   // states 2j, 2j+1
        lr[j]  = v2f{lamr[o], lamr[o + HD]};
        lim[j] = v2f{lami[o], lami[o + HD]};
        cr[j]  = v2f{cdr[o], cdr[o + HD]};
        nci[j] = v2f{-cdi[o], -cdi[o + HD]};
        sr[j]  = v2f{0.f, 0.f};
        si[j]  = v2f{0.f, 0.f};
    }

    // staging: 112 rows x 16 float4 = 1792 float4; thread covers ids
    // thr, thr+512, thr+1024, thr+1536(first half only)
    const size_t ubase = (size_t)b * LSEQ * HD + h0;
    float4 pre[4];

    {   // prologue: load tile 0
#pragma unroll
        for (int p = 0; p < 4; p++) {
            int f = thr + p * 512;
            if (f < TL * 16) {
                int row = f >> 4, col = (f & 15) * 4;
                pre[p] = *(const float4*)&u[ubase + (size_t)row * HD + col];
            }
        }
    }

    for (int t = 0; t < NT; t++) {
        __syncthreads();                  // prior tile's LDS reads done
#pragma unroll
        for (int p = 0; p < 4; p++) {
            int f = thr + p * 512;
            if (f < TL * 16) {
                int row = f >> 4, col = (f & 15) * 4;
                *(float4*)&tile[row * CHB + col] = pre[p];
            }
        }
        __syncthreads();                  // tile visible

        if (t + 1 < NT) {                 // issue next tile's loads NOW
            int l0n = (t + 1) * TL;
#pragma unroll
            for (int p = 0; p < 4; p++) {
                int f = thr + p * 512;
                if (f < TL * 16) {
                    int row = f >> 4, col = (f & 15) * 4;
                    pre[p] = *(const float4*)&u[ubase + (size_t)(l0n + row) * HD + col];
                }
            }
        }

        for (int lo = 0; lo < TL; lo += 8) {
#pragma unroll
            for (int lu = 0; lu < 8; lu++) {
                int l = lo + lu;
                float uv = tile[l * CHB + cl];
                v2f uv2 = v2f{uv, uv};
                v2f ya = v2f{0.f, 0.f}, yb = v2f{0.f, 0.f};
#pragma unroll
                for (int j = 0; j < NS2; j++) {
                    v2f t0  = pk_fma_na(lim[j], si[j], uv2);  // -li*si + uv
                    v2f nsr = pk_fma(lr[j], sr[j], t0);
                    v2f tmp = pk_mul(lim[j], sr[j]);
                    v2f nsi = pk_fma(lr[j], si[j], tmp);
                    sr[j] = nsr; si[j] = nsi;
                    ya = pk_fma(cr[j], nsr, ya);
                    yb = pk_fma(nci[j], nsi, yb);
                }
                v2f ys = ya + yb;
                float y = ys.x + ys.y;
                y = dpp_add<0xB1>(y);     // quad_perm xor 1
                y = dpp_add<0x4E>(y);     // quad_perm xor 2
                y = dpp_add<0x141>(y);    // row_half_mirror (8-lane total)
                if (q == 0) tile[l * CHB + cl] = fmaf(uv, dcoef, y);
            }
        }

        __syncthreads();                  // y writes visible
        {   // bulk store tile -> U (coalesced float4)
            size_t l0 = (size_t)t * TL;
#pragma unroll
            for (int p = 0; p < 4; p++) {
                int f = thr + p * 512;
                if (f < TL * 16) {
                    int row = f >> 4, col = (f & 15) * 4;
                    *(float4*)&u[ubase + (l0 + row) * HD + col] =
                        *(const float4*)&tile[row * CHB + col];
                }
            }
        }
    }
}

// ---------------------------------------------------------------------------
// In-place LayerNorm over H. One wave per (b,l) row; 8 floats per lane.
// ---------------------------------------------------------------------------
__global__ void ln_k(float* __restrict__ u, const float* __restrict__ gp,
                     const float* __restrict__ bp)
{
    int wid  = threadIdx.x >> 6;
    int lane = threadIdx.x & 63;
    size_t row = (size_t)blockIdx.x * 4 + wid;   // < BB*LSEQ exactly
    float* up = u + row * HD;

    float4 a0 = ((const float4*)up)[lane];
    float4 a1 = ((const float4*)up)[64 + lane];
    float v[8] = {a0.x, a0.y, a0.z, a0.w, a1.x, a1.y, a1.z, a1.w};
    int h0 = lane * 4, h1 = 256 + lane * 4;

    float s = 0.f;
#pragma unroll
    for (int j = 0; j < 8; j++) s += v[j];
#pragma unroll
    for (int m = 32; m >= 1; m >>= 1) s += __shfl_xor(s, m, 64);
    float mu = s * (1.0f / HD);

    float qq = 0.f;
#pragma unroll
    for (int j = 0; j < 8; j++) { float d = v[j] - mu; qq += d * d; }
#pragma unroll
    for (int m = 32; m >= 1; m >>= 1) qq += __shfl_xor(qq, m, 64);
    float rs = rsqrtf(qq * (1.0f / HD) + 1e-5f);

    float o[8];
#pragma unroll
    for (int j = 0; j < 8; j++) {
        int h = (j < 4) ? (h0 + j) : (h1 + j - 4);
        o[j] = fmaf((v[j] - mu) * rs, gp[h], bp[h]);
    }
    ((float4*)up)[lane]      = {o[0], o[1], o[2], o[3]};
    ((float4*)up)[64 + lane] = {o[4], o[5], o[6], o[7]};
}

// ---------------------------------------------------------------------------
// Mean-pool over L: pooled[b,h] = mean_l u[b,l,h]
// ---------------------------------------------------------------------------
__global__ void pool_k(const float* __restrict__ u, float* __restrict__ p)
{
    int g = blockIdx.x * blockDim.x + threadIdx.x;
    if (g >= BB * HD) return;
    int h = g & (HD - 1);
    int b = g >> 9;
    const float* up = u + (size_t)b * LSEQ * HD + h;
    float s = 0.f;
    for (int l = 0; l < LSEQ; l++) s += up[(size_t)l * HD];
    p[g] = s * (1.0f / LSEQ);
}

// ---------------------------------------------------------------------------
// Decoder: out[b,c] = pooled[b,:] @ dec_w[:,c] + dec_b[c]
// ---------------------------------------------------------------------------
__global__ void dec_k(const float* __restrict__ p, const float* __restrict__ w,
                      const float* __restrict__ bias, float* __restrict__ out)
{
    int t = blockIdx.x * blockDim.x + threadIdx.x;
    if (t >= BB * 10) return;
    int c = t % 10, b = t / 10;
    float acc = bias[c];
    const float* pb = p + b * HD;
    for (int h = 0; h < HD; h++) acc = fmaf(pb[h], w[h * 10 + c], acc);
    out[t] = acc;
}

// ---------------------------------------------------------------------------
extern "C" void kernel_launch(void* const* d_in, const int* in_sizes, int n_in,
                              void* d_out, int out_size, void* d_ws, size_t ws_size,
                              hipStream_t stream)
{
    const float* x   = (const float*)d_in[0];
    const float* ew  = (const float*)d_in[1];
    const float* eb  = (const float*)d_in[2];
    const float* ldt = (const float*)d_in[3];
    const float* lar = (const float*)d_in[4];
    const float* aim = (const float*)d_in[5];
    const float* cre = (const float*)d_in[6];
    const float* cim = (const float*)d_in[7];
    const float* Dp  = (const float*)d_in[8];
    const float* lng = (const float*)d_in[9];
    const float* lnb = (const float*)d_in[10];
    const float* fng = (const float*)d_in[11];
    const float* fnb = (const float*)d_in[12];
    const float* dw  = (const float*)d_in[13];
    const float* db  = (const float*)d_in[14];
    float* out = (float*)d_out;

    float* ws = (float*)d_ws;
    const size_t SZ = (size_t)BB * LSEQ * HD;   // 25,690,112 floats (103 MB)
    const size_t P  = (size_t)NLAY * NST * HD;  // 196,608 floats
    float* U  = ws;                              // residual stream, in-place
    float* LR = ws + SZ + 4 * HD;
    float* LI = LR + P;
    float* CR = LI + P;
    float* CI = CR + P;
    float* PO = CI + P;                          // BB*HD floats
    // total: ~106 MB

    precompute_k<<<(NLAY * HD * NST + 255) / 256, 256, 0, stream>>>(
        ldt, lar, aim, cre, cim, LR, LI, CR, CI);
    encoder_k<<<(int)((SZ + 255) / 256), 256, 0, stream>>>(x, ew, eb, U);

    for (int i = 0; i < NLAY; i++) {
        size_t po = (size_t)i * NST * HD;
        scan_k<<<BB * HD / CHB, 512, 0, stream>>>(
            U, LR + po, LI + po, CR + po, CI + po, Dp + i * HD);
        ln_k<<<BB * LSEQ / 4, 256, 0, stream>>>(U, lng + i * HD, lnb + i * HD);
    }
    ln_k<<<BB * LSEQ / 4, 256, 0, stream>>>(U, fng, fnb);
    pool_k<<<BB * HD / 256, 256, 0, stream>>>(U, PO);
    dec_k<<<(BB * 10 + 255) / 256, 256, 0, stream>>>(PO, dw, db, out);
}